// Round 4
// baseline (245.333 us; speedup 1.0000x reference)
//
#include <hip/hip_runtime.h>

// x: (B=32, H=256, W=256, C=16) float32, row-major.
// p[h][w] = mean over (b, c) of x[b][h][w][c]  (512 values)
// out = p >= 0.25 ? x*0.25/p : 1 - (0.75/(1-p))*(1-x)  ==  a*x + d
//
// Round-4 KEY: rounds 1-3 proved time is invariant to traffic (85 us with
// 384 MiB or 256 MiB cache-level traffic) -> the 4-MiB-strided 1 KiB gather
// + block barrier is pattern/latency-bound, not BW-bound. Restructure into
// linear streaming passes:
//   zero_p : p[64K] = 0 in d_ws
//   reduce : 1 block per contiguous 16 KiB row x[b][h]; lane sums its 16 c
//            via 4 coalesced float4 loads + shfl_xor(1,2); 1 atomicAdd per
//            (h,w) partial (2M atomics over 64K addrs - negligible).
//   apply  : pure elementwise grid-stride, linear float4 loads, nontemporal
//            float4 stores (keeps x L3-resident), rcp instead of div.

typedef float v4f __attribute__((ext_vector_type(4)));

#define ALPHA 0.25f

__global__ __launch_bounds__(256) void zero_p(float* __restrict__ p) {
  p[blockIdx.x * 256 + threadIdx.x] = 0.0f;
}

__global__ __launch_bounds__(256) void reduce_p(const float* __restrict__ x,
                                                float* __restrict__ p) {
  const int r = blockIdx.x;   // r = (b<<8)|h, 8192 rows of 16 KiB
  const int t = threadIdx.x;
  const float4* __restrict__ row = (const float4*)x + (long)r * 1024;

  float4 v[4];
#pragma unroll
  for (int j = 0; j < 4; ++j) v[j] = row[t + 256 * j];  // coalesced 1 KiB/wave

  float s[4];
#pragma unroll
  for (int j = 0; j < 4; ++j) s[j] = (v[j].x + v[j].y) + (v[j].z + v[j].w);

  // float4 index within row = t + 256j -> w = (t>>2) + 64j, c4 = t&3.
  // Sum the 4 c4 lanes sharing a w.
#pragma unroll
  for (int j = 0; j < 4; ++j) {
    s[j] += __shfl_xor(s[j], 1);
    s[j] += __shfl_xor(s[j], 2);
  }

  const int h = r & 255;
  if ((t & 3) == 0) {
    const int wbase = t >> 2;  // 0..63
#pragma unroll
    for (int j = 0; j < 4; ++j)
      atomicAdd(&p[h * 256 + wbase + 64 * j], s[j]);
  }
}

__global__ __launch_bounds__(256) void apply_k(const float* __restrict__ x,
                                               const float* __restrict__ p,
                                               float* __restrict__ out) {
  constexpr long STRIDE = 8192L * 256;  // threads in grid (float4 units)
  const long i0 = (long)blockIdx.x * 256 + threadIdx.x;

#pragma unroll
  for (int it = 0; it < 4; ++it) {
    const long i = i0 + (long)it * STRIDE;       // float4 index, 0..8M
    float4 v = ((const float4*)x)[i];
    const int hw = (int)((i >> 2) & 65535);      // (h<<8)|w
    const float pv = p[hw] * (1.0f / 512.0f);

    float a, d;
    if (pv >= ALPHA) {
      a = ALPHA * __builtin_amdgcn_rcpf(pv);
      d = 0.0f;
    } else {
      const float beta = (1.0f - ALPHA) * __builtin_amdgcn_rcpf(1.0f - pv);
      a = beta;
      d = 1.0f - beta;
    }

    v4f r;
    r.x = fmaf(a, v.x, d);
    r.y = fmaf(a, v.y, d);
    r.z = fmaf(a, v.z, d);
    r.w = fmaf(a, v.w, d);
    __builtin_nontemporal_store(r, (v4f*)out + i);
  }
}

extern "C" void kernel_launch(void* const* d_in, const int* in_sizes, int n_in,
                              void* d_out, int out_size, void* d_ws, size_t ws_size,
                              hipStream_t stream) {
  const float* x = (const float*)d_in[0];
  float* out = (float*)d_out;
  float* p = (float*)d_ws;  // 64K floats = 256 KiB partial-sum accumulator

  zero_p<<<dim3(256), dim3(256), 0, stream>>>(p);
  reduce_p<<<dim3(8192), dim3(256), 0, stream>>>(x, p);
  apply_k<<<dim3(8192), dim3(256), 0, stream>>>(x, p, out);
}